// Round 3
// baseline (7389.787 us; speedup 1.0000x reference)
//
#include <hip/hip_runtime.h>
#include <stdint.h>

// Problem constants
#define L_   6
#define D_   512
#define H_   8
#define DH_  64
#define MLP_ 2048
#define BB_  8
#define NN_  1024
#define ROWS_ 8192              // BB_*NN_
#define XSZ_  4194304           // ROWS_*D_   (output 0 size)
#define ATTN_LAYER_SZ_ 8388608  // BB_*NN_*NN_ (per-layer attn slice)

typedef union { float4 v; float f[4]; } f4u;

// ---------- LayerNorm: one wave per row (D=512 -> 8 elems/lane) ----------
__global__ __launch_bounds__(256) void k_ln(const float* __restrict__ x,
                                            const float* __restrict__ g,
                                            const float* __restrict__ bia,
                                            float* __restrict__ h) {
    const int row  = blockIdx.x * 4 + (threadIdx.x >> 6);
    const int lane = threadIdx.x & 63;
    const float* xr = x + (size_t)row * D_;
    float v[8]; float s = 0.f, sq = 0.f;
    #pragma unroll
    for (int j = 0; j < 8; j++) { v[j] = xr[lane + j * 64]; s += v[j]; sq += v[j] * v[j]; }
    #pragma unroll
    for (int off = 32; off >= 1; off >>= 1) {
        s  += __shfl_xor(s, off, 64);
        sq += __shfl_xor(sq, off, 64);
    }
    const float mean = s * (1.f / D_);
    const float var  = sq * (1.f / D_) - mean * mean;
    const float rstd = rsqrtf(var + 1e-5f);
    float* hr = h + (size_t)row * D_;
    #pragma unroll
    for (int j = 0; j < 8; j++) {
        int col = lane + j * 64;
        hr[col] = (v[j] - mean) * rstd * g[col] + bia[col];
    }
}

// ---------- tiled f32 GEMM: C[M,N] = A[M,K] @ B[K,N] (+bias,+res,+gelu) ----------
// 64x64 tile, BK=16, 256 threads, 4x4 micro-tile.
template<bool BIAS, bool RES, bool GELU>
__global__ __launch_bounds__(256) void k_gemm_nn(
        const float* __restrict__ A, int lda,
        const float* __restrict__ Bw, int ldb,
        const float* __restrict__ bias,
        const float* __restrict__ res,
        float* __restrict__ C, int ldc, int K) {
    __shared__ float As[16][68];
    __shared__ float Bs[16][68];
    const int tid = threadIdx.x;
    const int tm = tid >> 4, tn = tid & 15;
    const int m0 = blockIdx.y * 64, n0 = blockIdx.x * 64;
    const int arow = tid >> 2, ac4 = (tid & 3) * 4;
    const int brow = tid >> 4, bc4 = (tid & 15) * 4;
    const float* Ap = A  + (size_t)(m0 + arow) * lda + ac4;
    const float* Bp = Bw + (size_t)brow * ldb + n0 + bc4;
    float acc[4][4] = {};
    for (int k0 = 0; k0 < K; k0 += 16) {
        float4 av = *(const float4*)(Ap + k0);
        float4 bv = *(const float4*)(Bp + (size_t)k0 * ldb);
        As[ac4 + 0][arow] = av.x; As[ac4 + 1][arow] = av.y;
        As[ac4 + 2][arow] = av.z; As[ac4 + 3][arow] = av.w;
        *(float4*)&Bs[brow][bc4] = bv;
        __syncthreads();
        #pragma unroll
        for (int kk = 0; kk < 16; kk++) {
            f4u a, b;
            a.v = *(const float4*)&As[kk][tm * 4];
            b.v = *(const float4*)&Bs[kk][tn * 4];
            #pragma unroll
            for (int i = 0; i < 4; i++)
                #pragma unroll
                for (int j = 0; j < 4; j++)
                    acc[i][j] = fmaf(a.f[i], b.f[j], acc[i][j]);
        }
        __syncthreads();
    }
    #pragma unroll
    for (int i = 0; i < 4; i++) {
        const int row = m0 + tm * 4 + i;
        f4u o;
        #pragma unroll
        for (int j = 0; j < 4; j++) {
            const int col = n0 + tn * 4 + j;
            float vv = acc[i][j];
            if (BIAS) vv += bias[col];
            if (RES)  vv += res[(size_t)row * ldc + col];
            if (GELU) vv = 0.5f * vv * (1.f + erff(vv * 0.70710678118654752f));
            o.f[j] = vv;
        }
        *(float4*)(C + (size_t)row * ldc + n0 + tn * 4) = o.v;
    }
}

// ---------- full-dim scores: writes (q_b @ k_b^T) * 512^-0.5 to d_out attn slice ----------
__global__ __launch_bounds__(256) void k_scores(const float* __restrict__ qkv, float* __restrict__ sf) {
    const int b  = blockIdx.z;
    const int n0 = blockIdx.x * 64, m0 = blockIdx.y * 64;
    __shared__ float As[16][68];
    __shared__ float Bs[16][68];
    const int tid = threadIdx.x, tm = tid >> 4, tn = tid & 15;
    const int arow = tid >> 2, ac4 = (tid & 3) * 4;
    const float* Ap = qkv + ((size_t)b * NN_ + m0 + arow) * 1536 + ac4;         // q
    const float* Bp = qkv + ((size_t)b * NN_ + n0 + arow) * 1536 + 512 + ac4;   // k
    float acc[4][4] = {};
    for (int k0 = 0; k0 < 512; k0 += 16) {
        float4 av = *(const float4*)(Ap + k0);
        float4 bv = *(const float4*)(Bp + k0);
        As[ac4 + 0][arow] = av.x; As[ac4 + 1][arow] = av.y;
        As[ac4 + 2][arow] = av.z; As[ac4 + 3][arow] = av.w;
        Bs[ac4 + 0][arow] = bv.x; Bs[ac4 + 1][arow] = bv.y;
        Bs[ac4 + 2][arow] = bv.z; Bs[ac4 + 3][arow] = bv.w;
        __syncthreads();
        #pragma unroll
        for (int kk = 0; kk < 16; kk++) {
            f4u a, b2;
            a.v  = *(const float4*)&As[kk][tm * 4];
            b2.v = *(const float4*)&Bs[kk][tn * 4];
            #pragma unroll
            for (int i = 0; i < 4; i++)
                #pragma unroll
                for (int j = 0; j < 4; j++)
                    acc[i][j] = fmaf(a.f[i], b2.f[j], acc[i][j]);
        }
        __syncthreads();
    }
    const float scale = 0.044194173824159216f;  // 512^-0.5
    #pragma unroll
    for (int i = 0; i < 4; i++) {
        f4u o;
        #pragma unroll
        for (int j = 0; j < 4; j++) o.f[j] = acc[i][j] * scale;
        *(float4*)(sf + ((size_t)b << 20) + (size_t)(m0 + tm * 4 + i) * 1024 + n0 + tn * 4) = o.v;
    }
}

// ---------- row softmax (1024 cols) in place, f32 ----------
__global__ __launch_bounds__(256) void k_softmax(float* __restrict__ sf) {
    const int row = blockIdx.x;
    const int tid = threadIdx.x;
    float4* rp = (float4*)(sf + ((size_t)row << 10));
    const float4 v = rp[tid];
    float mx = fmaxf(fmaxf(v.x, v.y), fmaxf(v.z, v.w));
    #pragma unroll
    for (int off = 32; off >= 1; off >>= 1) mx = fmaxf(mx, __shfl_xor(mx, off, 64));
    __shared__ float rmax[4], rsum[4];
    if ((tid & 63) == 0) rmax[tid >> 6] = mx;
    __syncthreads();
    mx = fmaxf(fmaxf(rmax[0], rmax[1]), fmaxf(rmax[2], rmax[3]));
    float e0 = expf(v.x - mx), e1 = expf(v.y - mx), e2 = expf(v.z - mx), e3 = expf(v.w - mx);
    float s = e0 + e1 + e2 + e3;
    #pragma unroll
    for (int off = 32; off >= 1; off >>= 1) s += __shfl_xor(s, off, 64);
    if ((tid & 63) == 0) rsum[tid >> 6] = s;
    __syncthreads();
    s = rsum[0] + rsum[1] + rsum[2] + rsum[3];
    const float inv = 1.f / s;
    rp[tid] = make_float4(e0 * inv, e1 * inv, e2 * inv, e3 * inv);
}

// ---------- per-head flash attention ----------
// grid (qtile=16, head=8, batch=8), 256 threads. Ks buffer reused for P.
__global__ __launch_bounds__(256) void k_flash(const float* __restrict__ qkv, float* __restrict__ o) {
    const int qt = blockIdx.x, h = blockIdx.y, b = blockIdx.z;
    __shared__ float Qs[64][68];
    __shared__ float Ks[64][68];   // reused as P after S computed
    __shared__ float Vs[64][68];
    const int tid = threadIdx.x, tm = tid >> 4, tn = tid & 15;
    const float* qb = qkv + ((size_t)b * NN_ + qt * 64) * 1536 + h * 64;
    const float* kb = qkv + ((size_t)b * NN_) * 1536 + 512 + h * 64;
    const float* vb = kb + 512;
    for (int u = tid; u < 1024; u += 256) {
        int r = u >> 4, c4 = (u & 15) * 4;
        *(float4*)&Qs[r][c4] = *(const float4*)(qb + (size_t)r * 1536 + c4);
    }
    float m[4], l[4], O[4][4];
    #pragma unroll
    for (int i = 0; i < 4; i++) {
        m[i] = -INFINITY; l[i] = 0.f;
        #pragma unroll
        for (int j = 0; j < 4; j++) O[i][j] = 0.f;
    }
    for (int kt = 0; kt < 16; kt++) {
        __syncthreads();  // prev iter's Ks(P)/Vs reads done; Qs visible at kt=0
        for (int u = tid; u < 1024; u += 256) {
            int r = u >> 4, c4 = (u & 15) * 4;
            *(float4*)&Ks[r][c4] = *(const float4*)(kb + (size_t)(kt * 64 + r) * 1536 + c4);
            *(float4*)&Vs[r][c4] = *(const float4*)(vb + (size_t)(kt * 64 + r) * 1536 + c4);
        }
        __syncthreads();
        float S[4][4] = {};
        #pragma unroll
        for (int d4 = 0; d4 < 16; d4++) {
            f4u qv[4], kv[4];
            #pragma unroll
            for (int i = 0; i < 4; i++) qv[i].v = *(const float4*)&Qs[tm * 4 + i][d4 * 4];
            #pragma unroll
            for (int j = 0; j < 4; j++) kv[j].v = *(const float4*)&Ks[tn * 4 + j][d4 * 4];
            #pragma unroll
            for (int i = 0; i < 4; i++)
                #pragma unroll
                for (int j = 0; j < 4; j++)
                    #pragma unroll
                    for (int e = 0; e < 4; e++)
                        S[i][j] = fmaf(qv[i].f[e], kv[j].f[e], S[i][j]);
        }
        // online softmax (rows owned by 16-lane tm-groups within a wave)
        #pragma unroll
        for (int i = 0; i < 4; i++) {
            float rmx = -INFINITY;
            #pragma unroll
            for (int j = 0; j < 4; j++) { S[i][j] *= 0.125f; rmx = fmaxf(rmx, S[i][j]); }
            #pragma unroll
            for (int off = 1; off < 16; off <<= 1) rmx = fmaxf(rmx, __shfl_xor(rmx, off, 16));
            float mnew = fmaxf(m[i], rmx);
            float alpha = expf(m[i] - mnew);
            m[i] = mnew;
            float rs = 0.f;
            #pragma unroll
            for (int j = 0; j < 4; j++) { S[i][j] = expf(S[i][j] - mnew); rs += S[i][j]; }
            #pragma unroll
            for (int off = 1; off < 16; off <<= 1) rs += __shfl_xor(rs, off, 16);
            l[i] = l[i] * alpha + rs;
            #pragma unroll
            for (int j = 0; j < 4; j++) O[i][j] *= alpha;
        }
        __syncthreads();  // everyone done reading Ks as K
        #pragma unroll
        for (int i = 0; i < 4; i++)
            #pragma unroll
            for (int j = 0; j < 4; j++)
                Ks[tm * 4 + i][tn * 4 + j] = S[i][j];   // P
        __syncthreads();
        #pragma unroll
        for (int j4 = 0; j4 < 16; j4++) {
            f4u pv[4];
            #pragma unroll
            for (int i = 0; i < 4; i++) pv[i].v = *(const float4*)&Ks[tm * 4 + i][j4 * 4];
            #pragma unroll
            for (int jj = 0; jj < 4; jj++) {
                f4u vv;
                vv.v = *(const float4*)&Vs[j4 * 4 + jj][tn * 4];
                #pragma unroll
                for (int i = 0; i < 4; i++)
                    #pragma unroll
                    for (int e = 0; e < 4; e++)
                        O[i][e] = fmaf(pv[i].f[jj], vv.f[e], O[i][e]);
            }
        }
    }
    float* ob = o + ((size_t)b * NN_ + qt * 64) * 512 + h * 64;
    #pragma unroll
    for (int i = 0; i < 4; i++) {
        const float inv = 1.f / l[i];
        f4u ov;
        #pragma unroll
        for (int e = 0; e < 4; e++) ov.f[e] = O[i][e] * inv;
        *(float4*)(ob + (size_t)(tm * 4 + i) * 512 + tn * 4) = ov.v;
    }
}

extern "C" void kernel_launch(void* const* d_in, const int* in_sizes, int n_in,
                              void* d_out, int out_size, void* d_ws, size_t ws_size,
                              hipStream_t stream) {
    (void)in_sizes; (void)n_in; (void)out_size; (void)ws_size;
    const float* x_in  = (const float*)d_in[0];
    const float* ln1_g = (const float*)d_in[1];
    const float* ln1_b = (const float*)d_in[2];
    const float* w_qkv = (const float*)d_in[3];
    const float* w_o   = (const float*)d_in[4];
    const float* b_o   = (const float*)d_in[5];
    const float* ln2_g = (const float*)d_in[6];
    const float* ln2_b = (const float*)d_in[7];
    const float* w1    = (const float*)d_in[8];
    const float* b1    = (const float*)d_in[9];
    const float* w2    = (const float*)d_in[10];
    const float* b2    = (const float*)d_in[11];
    float* out_x    = (float*)d_out;            // [8192, 512]
    float* out_attn = (float*)d_out + XSZ_;     // [6, 8, 1024, 1024]

    // f32 workspace: x | h/o | union(qkv, ff) = ~101 MB
    float* xf   = (float*)d_ws;
    float* hbuf = xf + XSZ_;
    float* qkvb = hbuf + XSZ_;     // 8192*1536 floats (48 MB)
    float* ffb  = qkvb;            // aliases qkv region: 8192*2048 floats (64 MB); qkv dead by then

    hipMemcpyAsync(xf, x_in, (size_t)XSZ_ * sizeof(float), hipMemcpyDeviceToDevice, stream);
    for (int l = 0; l < L_; l++) {
        float* attn_l = out_attn + (size_t)l * ATTN_LAYER_SZ_;
        // PreNorm attention
        k_ln<<<2048, 256, 0, stream>>>(xf, ln1_g + l * 512, ln1_b + l * 512, hbuf);
        k_gemm_nn<false, false, false><<<dim3(24, 128), 256, 0, stream>>>(
            hbuf, 512, w_qkv + (size_t)l * 512 * 1536, 1536, nullptr, nullptr, qkvb, 1536, 512);
        k_scores<<<dim3(16, 16, 8), 256, 0, stream>>>(qkvb, attn_l);
        k_softmax<<<8192, 256, 0, stream>>>(attn_l);
        k_flash<<<dim3(16, 8, 8), 256, 0, stream>>>(qkvb, hbuf);   // o -> hbuf
        k_gemm_nn<true, true, false><<<dim3(8, 128), 256, 0, stream>>>(
            hbuf, 512, w_o + (size_t)l * 512 * 512, 512, b_o + l * 512, xf, xf, 512, 512);
        // PreNorm FFN
        k_ln<<<2048, 256, 0, stream>>>(xf, ln2_g + l * 512, ln2_b + l * 512, hbuf);
        k_gemm_nn<true, false, true><<<dim3(32, 128), 256, 0, stream>>>(
            hbuf, 512, w1 + (size_t)l * 512 * 2048, 2048, b1 + l * 2048, nullptr, ffb, 2048, 512);
        // last layer writes final x straight to d_out
        k_gemm_nn<true, true, false><<<dim3(8, 128), 256, 0, stream>>>(
            ffb, 2048, w2 + (size_t)l * 2048 * 512, 512, b2 + l * 512, xf,
            (l == L_ - 1) ? out_x : xf, 512, 2048);
    }
}